// Round 1
// baseline (31188.773 us; speedup 1.0000x reference)
//
#include <hip/hip_runtime.h>
#include <math.h>

#define VSIZE 32000
#define EDIM  200
#define HDIM  512
#define SLEN  64
#define TLEN  64
#define BATCH 64
#define NBLK  256
#define NTHR  512
#define VPB   125   // vocab rows per block in FC phase: 32000 / 256

struct Params {
  const int   *src, *target, *tf_mask;
  const float *enc_emb, *dec_emb;
  const float *eW_ih0, *eW_hh0, *eb_ih0, *eb_hh0;
  const float *eW_ih1, *eW_hh1, *eb_ih1, *eb_hh1;
  const float *dW_ih0, *dW_hh0, *db_ih0, *db_hh0;
  const float *dW_ih1, *dW_hh1, *db_ih1, *db_hh1;
  const float *fcW, *fcb;
  float *out;
  float *h0a, *h0b, *h1a, *h1b;   // blocked-transposed h state: elem(k,b) at (k>>2)*256 + b*4 + (k&3)
  float *cand_val;                // [64][NBLK]
  int   *cand_idx;                // [64][NBLK]
  int   *tok;                     // [64]
  unsigned *bar;                  // bar[0]=count, bar[1]=generation
};

__device__ __forceinline__ float dot4(const float4 a, const float4 b) {
  return a.x * b.x + a.y * b.y + a.z * b.z + a.w * b.w;
}
__device__ __forceinline__ float sigmoidf_(float x) { return 1.0f / (1.0f + expf(-x)); }

// Sense-reversing grid barrier with device(agent)-scope acq/rel. Each arriving
// block's acq_rel RMW writes back its XCD L2; the acquire spin-load invalidates
// the waiter's caches -> cross-XCD visibility of all pre-barrier stores.
__device__ __forceinline__ void gsync(unsigned* bar) {
  __syncthreads();
  if (threadIdx.x == 0) {
    __threadfence();
    unsigned gen = __hip_atomic_load(&bar[1], __ATOMIC_RELAXED, __HIP_MEMORY_SCOPE_AGENT);
    unsigned n = __hip_atomic_fetch_add(&bar[0], 1u, __ATOMIC_ACQ_REL, __HIP_MEMORY_SCOPE_AGENT);
    if (n == NBLK - 1u) {
      __hip_atomic_store(&bar[0], 0u, __ATOMIC_RELAXED, __HIP_MEMORY_SCOPE_AGENT);
      __hip_atomic_store(&bar[1], gen + 1u, __ATOMIC_RELEASE, __HIP_MEMORY_SCOPE_AGENT);
    } else {
      while (__hip_atomic_load(&bar[1], __ATOMIC_ACQUIRE, __HIP_MEMORY_SCOPE_AGENT) == gen)
        __builtin_amdgcn_s_sleep(1);
    }
    __threadfence();
  }
  __syncthreads();
}

// ---------------------------------------------------------------------------
// LSTM layer 0. Block owns h pair {blk*2, blk*2+1}. Thread = (b, hl, kc):
//   b = tid&63 (lane), wv = tid>>6, hl = wv&1, kc = wv>>1 (4-way K split).
// kc0 handles the x (embedding) part (50 f4); kc1..3 split the h part (43/43/42).
// Partials reduced through LDS; 128 threads apply gates, update LDS-resident c,
// write h_new to the blocked-transposed global buffer.
// ---------------------------------------------------------------------------
__device__ __forceinline__ void lstm_l0(
    const float* __restrict__ emb, const int* __restrict__ toks,
    const float* __restrict__ Wih, const float* __restrict__ Whh,
    const float* __restrict__ bih, const float* __restrict__ bhh,
    const float* __restrict__ h_in, float* __restrict__ h_out,
    float* cls, float* part, bool skip_h)
{
  const int tid = threadIdx.x;
  const int b = tid & 63, wv = tid >> 6;
  const int hl = wv & 1, kc = wv >> 1;
  const int h = blockIdx.x * 2 + hl;

  float a0 = 0.f, a1 = 0.f, a2 = 0.f, a3 = 0.f;
  if (kc == 0) {
    const int tokid = toks[b];
    const float4* xr = (const float4*)(emb + (size_t)tokid * EDIM);
    const float4* w0 = (const float4*)(Wih + (size_t)(h       ) * EDIM);
    const float4* w1 = (const float4*)(Wih + (size_t)(h +  512) * EDIM);
    const float4* w2 = (const float4*)(Wih + (size_t)(h + 1024) * EDIM);
    const float4* w3 = (const float4*)(Wih + (size_t)(h + 1536) * EDIM);
#pragma unroll 10
    for (int j = 0; j < EDIM / 4; ++j) {
      float4 x = xr[j];
      a0 += dot4(x, w0[j]); a1 += dot4(x, w1[j]);
      a2 += dot4(x, w2[j]); a3 += dot4(x, w3[j]);
    }
  } else if (!skip_h) {
    const int j0 = (kc == 1) ? 0 : (kc == 2) ? 43 : 86;
    const int j1 = (kc == 1) ? 43 : (kc == 2) ? 86 : 128;
    const float4* hr = (const float4*)h_in;
    const float4* u0 = (const float4*)(Whh + (size_t)(h       ) * HDIM);
    const float4* u1 = (const float4*)(Whh + (size_t)(h +  512) * HDIM);
    const float4* u2 = (const float4*)(Whh + (size_t)(h + 1024) * HDIM);
    const float4* u3 = (const float4*)(Whh + (size_t)(h + 1536) * HDIM);
    for (int j = j0; j < j1; ++j) {
      float4 x = hr[j * 64 + b];
      a0 += dot4(x, u0[j]); a1 += dot4(x, u1[j]);
      a2 += dot4(x, u2[j]); a3 += dot4(x, u3[j]);
    }
  }
  part[wv * 256 +       b] = a0;
  part[wv * 256 +  64 + b] = a1;
  part[wv * 256 + 128 + b] = a2;
  part[wv * 256 + 192 + b] = a3;
  __syncthreads();
  if (tid < 128) {
    const int bb = tid & 63, hl2 = tid >> 6;
    const int h2 = blockIdx.x * 2 + hl2;
    float g0 = 0.f, g1 = 0.f, g2 = 0.f, g3 = 0.f;
#pragma unroll
    for (int k = 0; k < 4; ++k) {
      const float* pp = part + (k * 2 + hl2) * 256;
      g0 += pp[bb]; g1 += pp[64 + bb]; g2 += pp[128 + bb]; g3 += pp[192 + bb];
    }
    g0 += bih[h2]        + bhh[h2];
    g1 += bih[h2 +  512] + bhh[h2 +  512];
    g2 += bih[h2 + 1024] + bhh[h2 + 1024];
    g3 += bih[h2 + 1536] + bhh[h2 + 1536];
    float c_old = cls[hl2 * 64 + bb];
    float gi = sigmoidf_(g0), gf = sigmoidf_(g1);
    float gg = tanhf(g2),     go = sigmoidf_(g3);
    float cn = gf * c_old + gi * gg;
    float hn = go * tanhf(cn);
    cls[hl2 * 64 + bb] = cn;
    h_out[(h2 >> 2) * 256 + bb * 4 + (h2 & 3)] = hn;
  }
  // no trailing __syncthreads needed: gsync() follows every phase
}

// LSTM layer 1: x = h0 (blocked-transposed), even 4-way K split (64 f4 each).
__device__ __forceinline__ void lstm_l1(
    const float* __restrict__ xT,
    const float* __restrict__ Wih, const float* __restrict__ Whh,
    const float* __restrict__ bih, const float* __restrict__ bhh,
    const float* __restrict__ h_in, float* __restrict__ h_out,
    float* cls, float* part, bool skip_h)
{
  const int tid = threadIdx.x;
  const int b = tid & 63, wv = tid >> 6;
  const int hl = wv & 1, kc = wv >> 1;
  const int h = blockIdx.x * 2 + hl;

  float a0 = 0.f, a1 = 0.f, a2 = 0.f, a3 = 0.f;
  if (kc < 2) {
    const int j0 = kc * 64;
    const float4* xr = (const float4*)xT;
    const float4* w0 = (const float4*)(Wih + (size_t)(h       ) * HDIM);
    const float4* w1 = (const float4*)(Wih + (size_t)(h +  512) * HDIM);
    const float4* w2 = (const float4*)(Wih + (size_t)(h + 1024) * HDIM);
    const float4* w3 = (const float4*)(Wih + (size_t)(h + 1536) * HDIM);
    for (int j = j0; j < j0 + 64; ++j) {
      float4 x = xr[j * 64 + b];
      a0 += dot4(x, w0[j]); a1 += dot4(x, w1[j]);
      a2 += dot4(x, w2[j]); a3 += dot4(x, w3[j]);
    }
  } else if (!skip_h) {
    const int j0 = (kc - 2) * 64;
    const float4* hr = (const float4*)h_in;
    const float4* u0 = (const float4*)(Whh + (size_t)(h       ) * HDIM);
    const float4* u1 = (const float4*)(Whh + (size_t)(h +  512) * HDIM);
    const float4* u2 = (const float4*)(Whh + (size_t)(h + 1024) * HDIM);
    const float4* u3 = (const float4*)(Whh + (size_t)(h + 1536) * HDIM);
    for (int j = j0; j < j0 + 64; ++j) {
      float4 x = hr[j * 64 + b];
      a0 += dot4(x, u0[j]); a1 += dot4(x, u1[j]);
      a2 += dot4(x, u2[j]); a3 += dot4(x, u3[j]);
    }
  }
  part[wv * 256 +       b] = a0;
  part[wv * 256 +  64 + b] = a1;
  part[wv * 256 + 128 + b] = a2;
  part[wv * 256 + 192 + b] = a3;
  __syncthreads();
  if (tid < 128) {
    const int bb = tid & 63, hl2 = tid >> 6;
    const int h2 = blockIdx.x * 2 + hl2;
    float g0 = 0.f, g1 = 0.f, g2 = 0.f, g3 = 0.f;
#pragma unroll
    for (int k = 0; k < 4; ++k) {
      const float* pp = part + (k * 2 + hl2) * 256;
      g0 += pp[bb]; g1 += pp[64 + bb]; g2 += pp[128 + bb]; g3 += pp[192 + bb];
    }
    g0 += bih[h2]        + bhh[h2];
    g1 += bih[h2 +  512] + bhh[h2 +  512];
    g2 += bih[h2 + 1024] + bhh[h2 + 1024];
    g3 += bih[h2 + 1536] + bhh[h2 + 1536];
    float c_old = cls[hl2 * 64 + bb];
    float gi = sigmoidf_(g0), gf = sigmoidf_(g1);
    float gg = tanhf(g2),     go = sigmoidf_(g3);
    float cn = gf * c_old + gi * gg;
    float hn = go * tanhf(cn);
    cls[hl2 * 64 + bb] = cn;
    h_out[(h2 >> 2) * 256 + bb * 4 + (h2 & 3)] = hn;
  }
}

// ---------------------------------------------------------------------------
// FC + argmax-partial. Block owns 125 vocab rows. Thread = (b = tid&63 lane,
// vl = tid>>6); each thread computes 16 logits (v = vstart + j*8 + vl) in ONE
// pass over h1 (single h1 read per wave), tracks its per-b running argmax
// (ascending v => strict > keeps first index), stages logits in a padded LDS
// tile, then stores them coalesced (lane -> consecutive v).
// ---------------------------------------------------------------------------
__device__ __forceinline__ void fc_phase(
    const float* __restrict__ h1T, const float* __restrict__ fcW,
    const float* __restrict__ fcb, float* __restrict__ out_slice,
    float* ltile, float* amv, int* ami,
    float* __restrict__ cand_val, int* __restrict__ cand_idx)
{
  const int tid = threadIdx.x;
  const int b = tid & 63, vl = tid >> 6;      // vl in [0,8)
  const int vstart = blockIdx.x * VPB;
  const float4* __restrict__ hr = (const float4*)h1T;

  const float4* wp[16];
  float acc[16];
#pragma unroll
  for (int j = 0; j < 16; ++j) {
    int vloc = j * 8 + vl;
    if (vloc > VPB - 1) vloc = VPB - 1;       // clamp: duplicate read, guarded below
    wp[j] = (const float4*)(fcW + (size_t)(vstart + vloc) * HDIM);
    acc[j] = 0.f;
  }
  for (int kb = 0; kb < HDIM / 4; ++kb) {
    float4 hv = hr[kb * 64 + b];
#pragma unroll
    for (int j = 0; j < 16; ++j) acc[j] += dot4(hv, wp[j][kb]);
  }

  float best = -INFINITY; int bidx = 0x7fffffff;
#pragma unroll
  for (int j = 0; j < 16; ++j) {
    const int vloc = j * 8 + vl;
    if (vloc < VPB) {
      const int v = vstart + vloc;
      const float val = acc[j] + fcb[v];
      ltile[vloc * 65 + b] = val;
      if (val > best) { best = val; bidx = v; }
    }
  }
  amv[vl * 64 + b] = best;
  ami[vl * 64 + b] = bidx;
  __syncthreads();

  if (tid < 64) {   // per-b reduce over the 8 vl groups, tie -> smaller v
    float bv = amv[tid]; int bi = ami[tid];
#pragma unroll
    for (int k = 1; k < 8; ++k) {
      float ov = amv[k * 64 + tid]; int oi = ami[k * 64 + tid];
      if (ov > bv || (ov == bv && oi < bi)) { bv = ov; bi = oi; }
    }
    cand_val[tid * NBLK + blockIdx.x] = bv;
    cand_idx[tid * NBLK + blockIdx.x] = bi;
  }

  // coalesced logits store: lane -> consecutive v within a 125-row stripe
  {
    const int vloc = tid & 127, bq = tid >> 7;
    if (vloc < VPB) {
#pragma unroll
      for (int bo = 0; bo < 16; ++bo) {
        const int bb = bo * 4 + bq;
        out_slice[(size_t)bb * VSIZE + vstart + vloc] = ltile[vloc * 65 + bb];
      }
    }
  }
}

// Final argmax over the 256 per-block candidates (blocks 0..63, one per b),
// then teacher-forcing select. Candidate v-ranges ascend with block index, so
// (greater) || (equal && smaller idx) preserves jnp.argmax first-index ties.
__device__ __forceinline__ void amax_phase(
    const float* __restrict__ cand_val, const int* __restrict__ cand_idx,
    const int* __restrict__ target_row, const int* __restrict__ tfp,
    int* __restrict__ tok, float* sv, int* si)
{
  if (blockIdx.x >= 64) return;
  const int b = blockIdx.x, tid = threadIdx.x;
  if (tid < 256) { sv[tid] = cand_val[b * NBLK + tid]; si[tid] = cand_idx[b * NBLK + tid]; }
  __syncthreads();
  for (int s = 128; s > 0; s >>= 1) {
    if (tid < s) {
      float ov = sv[tid + s]; int oi = si[tid + s];
      if (ov > sv[tid] || (ov == sv[tid] && oi < si[tid])) { sv[tid] = ov; si[tid] = oi; }
    }
    __syncthreads();
  }
  if (tid == 0) tok[b] = (*tfp > 0) ? target_row[b] : si[0];
}

__global__ void bar_init(unsigned* __restrict__ bar) {
  if (threadIdx.x < 2) bar[threadIdx.x] = 0u;
}

__global__ __launch_bounds__(NTHR, 2) void seq2seq_kernel(Params p)
{
  __shared__ float part[8 * 256];          // 8 KB   K-split partials
  __shared__ float ltile[VPB * 65];        // 32.5 KB logits transpose tile
  __shared__ float amv[512];
  __shared__ int   ami[512];
  __shared__ float sv[256];
  __shared__ int   si[256];
  __shared__ float c0ls[128], c1ls[128];   // block-owned LSTM cell state

  const int tid = threadIdx.x;
  if (tid < 128) { c0ls[tid] = 0.f; c1ls[tid] = 0.f; }

  // Zero output slice 0 (defined as zeros; never read in-kernel, no barrier needed).
  {
    float4* o4 = (float4*)p.out;
    const int total = BATCH * VSIZE / 4;   // 512000
    for (int i = blockIdx.x * NTHR + tid; i < total; i += NBLK * NTHR)
      o4[i] = make_float4(0.f, 0.f, 0.f, 0.f);
  }
  __syncthreads();

  float* h0bufs[2] = { p.h0a, p.h0b };
  float* h1bufs[2] = { p.h1a, p.h1b };

  // ---- Encoder (h/c start at zero: step 0 skips the recurrent term) ----
  for (int t = 0; t < SLEN; ++t) {
    const float* h0in = h0bufs[t & 1];  float* h0out = h0bufs[(t & 1) ^ 1];
    const float* h1in = h1bufs[t & 1];  float* h1out = h1bufs[(t & 1) ^ 1];
    lstm_l0(p.enc_emb, p.src + t * BATCH, p.eW_ih0, p.eW_hh0, p.eb_ih0, p.eb_hh0,
            h0in, h0out, c0ls, part, t == 0);
    gsync(p.bar);
    lstm_l1(h0out, p.eW_ih1, p.eW_hh1, p.eb_ih1, p.eb_hh1,
            h1in, h1out, c1ls, part, t == 0);
    gsync(p.bar);
  }
  // final encoder states now in bufs[0] (t=63 wrote out = bufs[0])

  if (blockIdx.x == 0 && tid < 64) p.tok[tid] = p.target[tid];  // x0 = target[0]
  gsync(p.bar);

  // ---- Decoder ----
  for (int j = 0; j < TLEN - 1; ++j) {
    const float* h0in = h0bufs[j & 1];  float* h0out = h0bufs[(j & 1) ^ 1];
    const float* h1in = h1bufs[j & 1];  float* h1out = h1bufs[(j & 1) ^ 1];
    lstm_l0(p.dec_emb, p.tok, p.dW_ih0, p.dW_hh0, p.db_ih0, p.db_hh0,
            h0in, h0out, c0ls, part, false);
    gsync(p.bar);
    lstm_l1(h0out, p.dW_ih1, p.dW_hh1, p.db_ih1, p.db_hh1,
            h1in, h1out, c1ls, part, false);
    gsync(p.bar);
    fc_phase(h1out, p.fcW, p.fcb, p.out + (size_t)(j + 1) * BATCH * VSIZE,
             ltile, amv, ami, p.cand_val, p.cand_idx);
    if (j < TLEN - 2) {
      gsync(p.bar);
      amax_phase(p.cand_val, p.cand_idx, p.target + (j + 1) * BATCH,
                 p.tf_mask + (j + 1), p.tok, sv, si);
      gsync(p.bar);
    }
  }
}

extern "C" void kernel_launch(void* const* d_in, const int* in_sizes, int n_in,
                              void* d_out, int out_size, void* d_ws, size_t ws_size,
                              hipStream_t stream)
{
  Params p;
  p.src     = (const int*)  d_in[0];
  p.target  = (const int*)  d_in[1];
  p.tf_mask = (const int*)  d_in[2];
  p.enc_emb = (const float*)d_in[3];
  p.dec_emb = (const float*)d_in[4];
  p.eW_ih0 = (const float*)d_in[5];  p.eW_hh0 = (const float*)d_in[6];
  p.eb_ih0 = (const float*)d_in[7];  p.eb_hh0 = (const float*)d_in[8];
  p.eW_ih1 = (const float*)d_in[9];  p.eW_hh1 = (const float*)d_in[10];
  p.eb_ih1 = (const float*)d_in[11]; p.eb_hh1 = (const float*)d_in[12];
  p.dW_ih0 = (const float*)d_in[13]; p.dW_hh0 = (const float*)d_in[14];
  p.db_ih0 = (const float*)d_in[15]; p.db_hh0 = (const float*)d_in[16];
  p.dW_ih1 = (const float*)d_in[17]; p.dW_hh1 = (const float*)d_in[18];
  p.db_ih1 = (const float*)d_in[19]; p.db_hh1 = (const float*)d_in[20];
  p.fcW    = (const float*)d_in[21];
  p.fcb    = (const float*)d_in[22];
  p.out = (float*)d_out;

  float* ws = (float*)d_ws;
  p.h0a = ws;
  p.h0b = ws + 32768;
  p.h1a = ws + 2 * 32768;
  p.h1b = ws + 3 * 32768;
  p.cand_val = ws + 4 * 32768;                    // 16384 floats
  p.cand_idx = (int*)(ws + 4 * 32768 + 16384);    // 16384 ints
  p.tok      = (int*)(ws + 4 * 32768 + 32768);    // 64 ints
  p.bar      = (unsigned*)(ws + 4 * 32768 + 32768 + 64);

  bar_init<<<1, 64, 0, stream>>>(p.bar);

  void* args[] = { (void*)&p };
  hipError_t err = hipLaunchCooperativeKernel((void*)seq2seq_kernel,
                                              dim3(NBLK), dim3(NTHR), args, 0, stream);
  if (err != hipSuccess) {
    // Fallback: 256 blocks x 512 threads (1 block/CU by resources) co-resides
    // on an otherwise-idle 256-CU device; barrier logic is identical.
    hipLaunchKernelGGL(seq2seq_kernel, dim3(NBLK), dim3(NTHR), 0, stream, p);
  }
}